// Round 2
// baseline (4253.391 us; speedup 1.0000x reference)
//
#include <hip/hip_runtime.h>
#include <hip/hip_fp16.h>
#include <cstdint>
#include <cstddef>

// Problem constants (T, B, V, HID, L) from the reference.
#define TT 1024
#define BB 64
#define VV 256
#define HH 512
static const size_t TBH = (size_t)TT * BB * HH;   // 33,554,432 floats

#define AGENT __HIP_MEMORY_SCOPE_AGENT

typedef _Float16 half2v __attribute__((ext_vector_type(2)));
union U32H2 { unsigned u; half2v h; };

__device__ __forceinline__ unsigned pack_f16x2(float a, float b) {
    __half ha = __float2half_rn(a);
    __half hb = __float2half_rn(b);
    return (unsigned)__half_as_ushort(ha) | ((unsigned)__half_as_ushort(hb) << 16);
}

__device__ __forceinline__ float tanh_fast(float x) {
    // tanh(x) = sign(x) * (1 - e^-2|x|) / (1 + e^-2|x|)
    float ax = fabsf(x);
    float e = __expf(-2.0f * ax);
    float r = (1.0f - e) * __builtin_amdgcn_rcpf(1.0f + e);
    return copysignf(r, x);
}

__device__ __forceinline__ float fdot2(unsigned w, unsigned h, float acc) {
    U32H2 uw; uw.u = w;
    U32H2 uh; uh.u = h;
#if __has_builtin(__builtin_amdgcn_fdot2)
    return __builtin_amdgcn_fdot2(uw.h, uh.h, acc, false);
#else
    return acc + (float)uw.h[0] * (float)uh.h[0] + (float)uw.h[1] * (float)uh.h[1];
#endif
}

// h-LDS swizzle: pair j (dword) lives at dword index j ^ (((j>>5)&7)<<2).
// Involution (bits 5..7 unchanged). A wave's ds_read_b128 at fixed q across
// kg=0..7 then hits bank groups ((q^kg)*4) -- all distinct -> conflict-free.
__device__ __forceinline__ int swz_us(int r) {     // row -> ushort index
    int j = r >> 1;
    int js = j ^ (((j >> 5) & 7) << 2);
    return (js << 1) | (r & 1);
}

// ---------------------------------------------------------------------------
// Weight prep:
//  Wq0/Wq1 : recurrent Wh rows as f16x2 k-pairs   [512 rows][256 pairs]
//  Wp0/Wp1 : input-proj Wx^T as f16x2 k-pairs     [K/2 pairs][512 cols]
// ---------------------------------------------------------------------------
__global__ void pack_weights(const float* __restrict__ Wnet,
                             const float* __restrict__ Wdeep,
                             unsigned* __restrict__ Wq0, unsigned* __restrict__ Wq1,
                             unsigned* __restrict__ Wp0, unsigned* __restrict__ Wp1) {
    int id = blockIdx.x * 256 + threadIdx.x;
    const int NQ  = HH * (HH / 2);     // 131072
    const int NP0 = (VV / 2) * HH;     // 65536
    const int NP1 = (HH / 2) * HH;     // 131072
    if (id < NQ) {
        int i = id >> 8, jp = id & 255;
        const float* row = Wnet + (size_t)i * (VV + HH) + VV;   // Wh0[i][:]
        Wq0[id] = pack_f16x2(row[2 * jp], row[2 * jp + 1]);
        return;
    }
    id -= NQ;
    if (id < NQ) {
        int i = id >> 8, jp = id & 255;
        const float* row = Wdeep + (size_t)i * (2 * HH) + HH;   // Wh1[i][:]
        Wq1[id] = pack_f16x2(row[2 * jp], row[2 * jp + 1]);
        return;
    }
    id -= NQ;
    if (id < NP0) {
        int k2 = id >> 9, n = id & 511;                          // Wx0[n][2k2..]
        const float* row = Wnet + (size_t)n * (VV + HH);
        Wp0[id] = pack_f16x2(row[2 * k2], row[2 * k2 + 1]);
        return;
    }
    id -= NP0;
    if (id < NP1) {
        int k2 = id >> 9, n = id & 511;                          // Wx1[n][2k2..]
        const float* row = Wdeep + (size_t)n * (2 * HH);
        Wp1[id] = pack_f16x2(row[2 * k2], row[2 * k2 + 1]);
        return;
    }
}

// ---------------------------------------------------------------------------
// Input-projection GEMM (f16 dot2): C[M,512] = A[M,K] @ Wx^T + bias.
// ---------------------------------------------------------------------------
__device__ __forceinline__ void dot8(float* acc, unsigned a, uint4 w0, uint4 w1) {
    acc[0] = fdot2(w0.x, a, acc[0]);
    acc[1] = fdot2(w0.y, a, acc[1]);
    acc[2] = fdot2(w0.z, a, acc[2]);
    acc[3] = fdot2(w0.w, a, acc[3]);
    acc[4] = fdot2(w1.x, a, acc[4]);
    acc[5] = fdot2(w1.y, a, acc[5]);
    acc[6] = fdot2(w1.z, a, acc[6]);
    acc[7] = fdot2(w1.w, a, acc[7]);
}

__launch_bounds__(1024)
__global__ void xproj_f16(const float* __restrict__ A,
                          const unsigned* __restrict__ Wp,   // [K/2][512] f16x2
                          const float* __restrict__ bias,
                          float* __restrict__ C, int K) {
    extern __shared__ unsigned As2[];      // 32 rows * K/2 pairs
    const int m0 = blockIdx.x * 32;
    const int t = threadIdx.x;
    const int K2 = K >> 1;

    const int nf4 = 8 * K;                 // 32*K/4
    const float4* Ag = (const float4*)(A + (size_t)m0 * K);
    for (int idx = t; idx < nf4; idx += 1024) {
        float4 v = Ag[idx];
        As2[idx * 2]     = pack_f16x2(v.x, v.y);
        As2[idx * 2 + 1] = pack_f16x2(v.z, v.w);
    }
    __syncthreads();

    const int rg = t >> 6;                 // 2 rows per thread
    const int n0 = (t & 63) * 8;

    float acc0[8] = {0, 0, 0, 0, 0, 0, 0, 0};
    float acc1[8] = {0, 0, 0, 0, 0, 0, 0, 0};

    const unsigned* a0p = As2 + (size_t)(rg * 2) * K2;
    const unsigned* a1p = a0p + K2;

#pragma unroll 4
    for (int k2 = 0; k2 < K2; k2 += 2) {
        unsigned a00 = a0p[k2], a01 = a0p[k2 + 1];
        unsigned a10 = a1p[k2], a11 = a1p[k2 + 1];
        const uint4 w00 = *(const uint4*)(Wp + (size_t)k2 * 512 + n0);
        const uint4 w01 = *(const uint4*)(Wp + (size_t)k2 * 512 + n0 + 4);
        const uint4 w10 = *(const uint4*)(Wp + (size_t)(k2 + 1) * 512 + n0);
        const uint4 w11 = *(const uint4*)(Wp + (size_t)(k2 + 1) * 512 + n0 + 4);
        dot8(acc0, a00, w00, w01);
        dot8(acc1, a10, w00, w01);
        dot8(acc0, a01, w10, w11);
        dot8(acc1, a11, w10, w11);
    }

    float bv[8];
#pragma unroll
    for (int c = 0; c < 8; ++c) bv[c] = bias[n0 + c];

    float* Crow0 = C + (size_t)(m0 + rg * 2) * 512 + n0;
    float* Crow1 = Crow0 + 512;
    *(float4*)(Crow0)     = make_float4(acc0[0] + bv[0], acc0[1] + bv[1], acc0[2] + bv[2], acc0[3] + bv[3]);
    *(float4*)(Crow0 + 4) = make_float4(acc0[4] + bv[4], acc0[5] + bv[5], acc0[6] + bv[6], acc0[7] + bv[7]);
    *(float4*)(Crow1)     = make_float4(acc1[0] + bv[0], acc1[1] + bv[1], acc1[2] + bv[2], acc1[3] + bv[3]);
    *(float4*)(Crow1 + 4) = make_float4(acc1[4] + bv[4], acc1[5] + bv[5], acc1[6] + bv[6], acc1[7] + bv[7]);
}

// ---------------------------------------------------------------------------
// RNN scan v4: ROW-split (not K-split), 2 WGs per batch element.
// WG s owns rows [s*256, s*256+256) with FULL K.  Wave w, lane=(rowsub,kg):
// thread computes 4 rows {s*256+w*32+rowsub+8j} over k-pairs [kg*32,kg*32+32)
// -> 128 v_dot2, 128 weight dwords (same residency footprint as v3, which the
// allocator kept in the unified VGPR/AGPR file: VGPR_Count=76 both rounds with
// no refetch stall).  No v_readlane: h comes as per-lane LDS chunks
// (8x ds_read_b128, XOR-swizzled conflict-free) and partial sums reduce via
// 3x shfl_xor butterfly (masks 8/16/32) -> VALU/step halves vs v3 (256->~150).
// Cross-WG: exchange 256 finalized h values per direction (tagged u64,
// relaxed agent atomics, parity double-buffer; store-branch before poll-branch
// so stores always issue before any spin).  One __syncthreads per step.
// ---------------------------------------------------------------------------
__launch_bounds__(512, 1)
__global__ void rnn_scan4(const unsigned* __restrict__ Wq,   // [512][256] f16x2
                          const float* __restrict__ h0,      // [B][512]
                          float* __restrict__ states,        // [T][B][512] in:pre out:h
                          float* __restrict__ last,          // [B][512]
                          unsigned long long* __restrict__ X) { // [B][2 side][2 par][256]
    __shared__ unsigned short hsh[2][512];   // full h as f16, parity-buffered

    const int wg = blockIdx.x;
    const int b = wg & 63;          // pair (b, b+64) -> same XCD under %8 rr
    const int s = wg >> 6;          // row-half owner
    const int tid = threadIdx.x;
    const int w = tid >> 6;
    const int lane = tid & 63;
    const int rowsub = lane & 7;
    const int kg = lane >> 3;       // k-chunk (pairs [kg*32, kg*32+32))
    const int rbase = s * 256 + w * 32 + rowsub;      // rows rbase+8j, j=0..3
    const bool is_fin = (kg < 4);   // finalizer lanes (1 row each)
    const int rfin = rbase + 8 * kg;                  // valid when is_fin
    const int fidx = w * 32 + rowsub + 8 * kg;        // local slot 0..255
    const int pidx = w * 32 + (lane & 31);            // poll slot 0..255
    const int rpoll = (1 - s) * 256 + pidx;           // partner row

    // --- weights: 4 rows x 32 pairs = 32 uint4, loaded once ---
    uint4 wreg[4][8];
#pragma unroll
    for (int j = 0; j < 4; ++j) {
        const uint4* Wr = (const uint4*)(Wq + (size_t)(rbase + 8 * j) * 256 + kg * 32);
#pragma unroll
        for (int q = 0; q < 8; ++q) wreg[j][q] = Wr[q];
    }

    // --- prologue: stage h0 into hsh[1] (parity of "t=-1"), load hv ---
    hsh[1][swz_us(tid)] = __half_as_ushort(__float2half_rn(h0[(size_t)b * HH + tid]));
    __syncthreads();
    uint4 hv[8];
    {
        const uint4* hb = (const uint4*)hsh[1];
#pragma unroll
        for (int q = 0; q < 8; ++q) hv[q] = hb[kg * 8 + (q ^ kg)];
    }

    // exchange slot bases (parity-selected per step)
    unsigned long long* slotW_A = X + (((size_t)(b * 2 + s) * 2 + 0) << 8) + fidx;
    unsigned long long* slotW_B = slotW_A + 256;
    unsigned long long* slotR_A = X + (((size_t)(b * 2 + (1 - s)) * 2 + 0) << 8) + pidx;
    unsigned long long* slotR_B = slotR_A + 256;

    size_t base = (size_t)b * HH;
    const size_t tstride = (size_t)BB * HH;

    float pre_cur = 0.f;
    if (is_fin) pre_cur = states[base + rfin];

    float hlast = 0.f;
    for (int t = 0; t < TT; ++t) {
        float pre_nxt = 0.f;
        if (is_fin && t + 1 < TT) pre_nxt = states[base + tstride + rfin];

        // 4 independent dot chains (rows) x 32 fdot2 each
        float a0 = 0.f, a1 = 0.f, a2 = 0.f, a3 = 0.f;
#pragma unroll
        for (int q = 0; q < 8; ++q) {
            const uint4 hq = hv[q];
            a0 = fdot2(wreg[0][q].x, hq.x, a0);
            a0 = fdot2(wreg[0][q].y, hq.y, a0);
            a0 = fdot2(wreg[0][q].z, hq.z, a0);
            a0 = fdot2(wreg[0][q].w, hq.w, a0);
            a1 = fdot2(wreg[1][q].x, hq.x, a1);
            a1 = fdot2(wreg[1][q].y, hq.y, a1);
            a1 = fdot2(wreg[1][q].z, hq.z, a1);
            a1 = fdot2(wreg[1][q].w, hq.w, a1);
            a2 = fdot2(wreg[2][q].x, hq.x, a2);
            a2 = fdot2(wreg[2][q].y, hq.y, a2);
            a2 = fdot2(wreg[2][q].z, hq.z, a2);
            a2 = fdot2(wreg[2][q].w, hq.w, a2);
            a3 = fdot2(wreg[3][q].x, hq.x, a3);
            a3 = fdot2(wreg[3][q].y, hq.y, a3);
            a3 = fdot2(wreg[3][q].z, hq.z, a3);
            a3 = fdot2(wreg[3][q].w, hq.w, a3);
        }
        // butterfly across kg lanes (bits 3..5): every lane gets full row sums
        a0 += __shfl_xor(a0, 8);  a0 += __shfl_xor(a0, 16);  a0 += __shfl_xor(a0, 32);
        a1 += __shfl_xor(a1, 8);  a1 += __shfl_xor(a1, 16);  a1 += __shfl_xor(a1, 32);
        a2 += __shfl_xor(a2, 8);  a2 += __shfl_xor(a2, 16);  a2 += __shfl_xor(a2, 32);
        a3 += __shfl_xor(a3, 8);  a3 += __shfl_xor(a3, 16);  a3 += __shfl_xor(a3, 32);

        const int p = t & 1;
        if (is_fin) {
            // static select a[kg] (runtime index would spill to scratch)
            float af = (kg == 0) ? a0 : (kg == 1) ? a1 : (kg == 2) ? a2 : a3;
            float h = tanh_fast(pre_cur + af);
            hlast = h;
            states[base + rfin] = h;                       // coalesced 128B/wave
            unsigned long long msg = ((unsigned long long)(unsigned)(t + 1) << 32)
                                   | (unsigned long long)__float_as_uint(h);
            __hip_atomic_store(p ? slotW_B : slotW_A, msg, __ATOMIC_RELAXED, AGENT);
            hsh[p][swz_us(rfin)] = __half_as_ushort(__float2half_rn(h));
        } else {
            unsigned long long* slot = p ? slotR_B : slotR_A;
            unsigned long long v;
            do {
                v = __hip_atomic_load(slot, __ATOMIC_RELAXED, AGENT);
            } while ((unsigned)(v >> 32) != (unsigned)(t + 1));
            float hp_ = __uint_as_float((unsigned)v);
            hsh[p][swz_us(rpoll)] = __half_as_ushort(__float2half_rn(hp_));
        }
        __syncthreads();

        // reload h chunk for next step (bank-conflict-free via swizzle)
        const uint4* hb = (const uint4*)hsh[p];
#pragma unroll
        for (int q = 0; q < 8; ++q) hv[q] = hb[kg * 8 + (q ^ kg)];

        pre_cur = pre_nxt;
        base += tstride;
    }

    if (is_fin) last[(size_t)b * HH + rfin] = hlast;
}

// ---------------------------------------------------------------------------
extern "C" void kernel_launch(void* const* d_in, const int* in_sizes, int n_in,
                              void* d_out, int out_size, void* d_ws, size_t ws_size,
                              hipStream_t stream) {
    (void)in_sizes; (void)n_in; (void)out_size; (void)ws_size;
    const float* inputs = (const float*)d_in[0];   // (T,B,V)
    const float* H      = (const float*)d_in[1];   // (L,B,HID)
    const float* Wnet   = (const float*)d_in[2];   // (HID, V+HID)
    const float* bnet   = (const float*)d_in[3];   // (HID,)
    const float* Wdeep  = (const float*)d_in[4];   // (HID, 2*HID)
    const float* bdeep  = (const float*)d_in[5];   // (HID,)
    float* out = (float*)d_out;

    // workspace layout (X first for 8B alignment); ~2.3 MB total
    unsigned long long* X = (unsigned long long*)d_ws;  // 64*2*2*256 u64 = 512 KB
    unsigned* Wq0 = (unsigned*)(X + 64 * 2 * 2 * 256);  // 131072 u32
    unsigned* Wq1 = Wq0 + HH * (HH / 2);                // 131072 u32
    unsigned* Wp0 = Wq1 + HH * (HH / 2);                // 65536 u32
    unsigned* Wp1 = Wp0 + (VV / 2) * HH;                // 131072 u32

    // 1) pack weights (458752 ids / 256 = 1792 blocks)
    hipLaunchKernelGGL(pack_weights, dim3(1792), dim3(256), 0, stream,
                       Wnet, Wdeep, Wq0, Wq1, Wp0, Wp1);

    // 2) pre0 = inputs @ Wx0^T + b_net  -> d_out[0:TBH]
    hipLaunchKernelGGL(xproj_f16, dim3((TT * BB) / 32), dim3(1024),
                       32 * (VV / 2) * sizeof(unsigned), stream,
                       inputs, Wp0, bnet, out, VV);

    // 3) layer-0 scan
    hipLaunchKernelGGL(rnn_scan4, dim3(128), dim3(512), 0, stream,
                       Wq0, H, out, out + TBH, X);

    // 4) pre1 = states0 @ Wx1^T + b_deep (in-place over d_out)
    hipLaunchKernelGGL(xproj_f16, dim3((TT * BB) / 32), dim3(1024),
                       32 * (HH / 2) * sizeof(unsigned), stream,
                       out, Wp1, bdeep, out, HH);

    // 5) layer-1 scan (X reusable: tags must arrive sequentially, so stale
    //    tag collisions from the previous scan are unreachable)
    hipLaunchKernelGGL(rnn_scan4, dim3(128), dim3(512), 0, stream,
                       Wq1, H + (size_t)BB * HH, out, out + TBH + (size_t)BB * HH, X);
}

// Round 4
// 4159.766 us; speedup vs baseline: 1.0225x; 1.0225x over previous
//
#include <hip/hip_runtime.h>
#include <hip/hip_fp16.h>
#include <cstdint>
#include <cstddef>

// Problem constants (T, B, V, HID, L) from the reference.
#define TT 1024
#define BB 64
#define VV 256
#define HH 512
static const size_t TBH = (size_t)TT * BB * HH;   // 33,554,432 floats

#define AGENT __HIP_MEMORY_SCOPE_AGENT

typedef _Float16 half2v __attribute__((ext_vector_type(2)));
union U32H2 { unsigned u; half2v h; };

__device__ __forceinline__ unsigned pack_f16x2(float a, float b) {
    __half ha = __float2half_rn(a);
    __half hb = __float2half_rn(b);
    return (unsigned)__half_as_ushort(ha) | ((unsigned)__half_as_ushort(hb) << 16);
}

__device__ __forceinline__ float tanh_fast(float x) {
    // tanh(x) = sign(x) * (1 - e^-2|x|) / (1 + e^-2|x|)
    float ax = fabsf(x);
    float e = __expf(-2.0f * ax);
    float r = (1.0f - e) * __builtin_amdgcn_rcpf(1.0f + e);
    return copysignf(r, x);
}

__device__ __forceinline__ float fdot2(unsigned w, unsigned h, float acc) {
    U32H2 uw; uw.u = w;
    U32H2 uh; uh.u = h;
#if __has_builtin(__builtin_amdgcn_fdot2)
    return __builtin_amdgcn_fdot2(uw.h, uh.h, acc, false);
#else
    return acc + (float)uw.h[0] * (float)uh.h[0] + (float)uw.h[1] * (float)uh.h[1];
#endif
}

// h-LDS swizzle: pair j (dword) lives at dword index j ^ (((j>>5)&7)<<2).
// Involution; preserves uint4 groups (XOR is a multiple of 4 dwords). A
// wave's uint4 read at fixed q across kg=0..7 hits bank-quads (q^kg) -- all
// distinct -> conflict-free; the 8 lanes sharing kg broadcast (same addr).
__device__ __forceinline__ int swz_us(int r) {     // row -> ushort index
    int j = r >> 1;
    int js = j ^ (((j >> 5) & 7) << 2);
    return (js << 1) | (r & 1);
}

// All-VALU butterfly sum over lane bits 3..5 (the kg dimension): keeps the
// reduction OFF the LDS pipe (which is saturated by weight ds_read_b128).
//  lane^8 : DPP row_ror:8 (rotation within each 16-lane row == xor 8)
//  lane^16: gfx950 v_permlane16_swap (swap adjacent 16-rows)
//  lane^32: gfx950 v_permlane32_swap (swap 32-halves)
// permlaneN_swap(x, x) returns {a,b} with a[l]+b[l] == x[l] + x[l^N] for all l.
__device__ __forceinline__ float bsum8(float v) {
    int d = __builtin_amdgcn_update_dpp(0, __float_as_int(v), 0x128, 0xF, 0xF, true);
    v += __int_as_float(d);
#if __has_builtin(__builtin_amdgcn_permlane16_swap) && __has_builtin(__builtin_amdgcn_permlane32_swap)
    {
        auto r1 = __builtin_amdgcn_permlane16_swap(__float_as_uint(v), __float_as_uint(v), false, false);
        v = __uint_as_float(r1[0]) + __uint_as_float(r1[1]);
        auto r2 = __builtin_amdgcn_permlane32_swap(__float_as_uint(v), __float_as_uint(v), false, false);
        v = __uint_as_float(r2[0]) + __uint_as_float(r2[1]);
    }
#else
    int l = (int)(threadIdx.x & 63);
    v += __int_as_float(__builtin_amdgcn_ds_bpermute((l ^ 16) << 2, __float_as_int(v)));
    v += __int_as_float(__builtin_amdgcn_ds_bpermute((l ^ 32) << 2, __float_as_int(v)));
#endif
    return v;
}

// ---------------------------------------------------------------------------
// Weight prep:
//  Wq0/Wq1 : recurrent Wh rows as f16x2 k-pairs   [512 rows][256 pairs]
//  Wp0/Wp1 : input-proj Wx^T as f16x2 k-pairs     [K/2 pairs][512 cols]
// ---------------------------------------------------------------------------
__global__ void pack_weights(const float* __restrict__ Wnet,
                             const float* __restrict__ Wdeep,
                             unsigned* __restrict__ Wq0, unsigned* __restrict__ Wq1,
                             unsigned* __restrict__ Wp0, unsigned* __restrict__ Wp1) {
    int id = blockIdx.x * 256 + threadIdx.x;
    const int NQ  = HH * (HH / 2);     // 131072
    const int NP0 = (VV / 2) * HH;     // 65536
    const int NP1 = (HH / 2) * HH;     // 131072
    if (id < NQ) {
        int i = id >> 8, jp = id & 255;
        const float* row = Wnet + (size_t)i * (VV + HH) + VV;   // Wh0[i][:]
        Wq0[id] = pack_f16x2(row[2 * jp], row[2 * jp + 1]);
        return;
    }
    id -= NQ;
    if (id < NQ) {
        int i = id >> 8, jp = id & 255;
        const float* row = Wdeep + (size_t)i * (2 * HH) + HH;   // Wh1[i][:]
        Wq1[id] = pack_f16x2(row[2 * jp], row[2 * jp + 1]);
        return;
    }
    id -= NQ;
    if (id < NP0) {
        int k2 = id >> 9, n = id & 511;                          // Wx0[n][2k2..]
        const float* row = Wnet + (size_t)n * (VV + HH);
        Wp0[id] = pack_f16x2(row[2 * k2], row[2 * k2 + 1]);
        return;
    }
    id -= NP0;
    if (id < NP1) {
        int k2 = id >> 9, n = id & 511;                          // Wx1[n][2k2..]
        const float* row = Wdeep + (size_t)n * (2 * HH);
        Wp1[id] = pack_f16x2(row[2 * k2], row[2 * k2 + 1]);
        return;
    }
}

// ---------------------------------------------------------------------------
// Input-projection GEMM (f16 dot2): C[M,512] = A[M,K] @ Wx^T + bias.
// ---------------------------------------------------------------------------
__device__ __forceinline__ void dot8(float* acc, unsigned a, uint4 w0, uint4 w1) {
    acc[0] = fdot2(w0.x, a, acc[0]);
    acc[1] = fdot2(w0.y, a, acc[1]);
    acc[2] = fdot2(w0.z, a, acc[2]);
    acc[3] = fdot2(w0.w, a, acc[3]);
    acc[4] = fdot2(w1.x, a, acc[4]);
    acc[5] = fdot2(w1.y, a, acc[5]);
    acc[6] = fdot2(w1.z, a, acc[6]);
    acc[7] = fdot2(w1.w, a, acc[7]);
}

__launch_bounds__(1024)
__global__ void xproj_f16(const float* __restrict__ A,
                          const unsigned* __restrict__ Wp,   // [K/2][512] f16x2
                          const float* __restrict__ bias,
                          float* __restrict__ C, int K) {
    extern __shared__ unsigned As2[];      // 32 rows * K/2 pairs
    const int m0 = blockIdx.x * 32;
    const int t = threadIdx.x;
    const int K2 = K >> 1;

    const int nf4 = 8 * K;                 // 32*K/4
    const float4* Ag = (const float4*)(A + (size_t)m0 * K);
    for (int idx = t; idx < nf4; idx += 1024) {
        float4 v = Ag[idx];
        As2[idx * 2]     = pack_f16x2(v.x, v.y);
        As2[idx * 2 + 1] = pack_f16x2(v.z, v.w);
    }
    __syncthreads();

    const int rg = t >> 6;                 // 2 rows per thread
    const int n0 = (t & 63) * 8;

    float acc0[8] = {0, 0, 0, 0, 0, 0, 0, 0};
    float acc1[8] = {0, 0, 0, 0, 0, 0, 0, 0};

    const unsigned* a0p = As2 + (size_t)(rg * 2) * K2;
    const unsigned* a1p = a0p + K2;

#pragma unroll 4
    for (int k2 = 0; k2 < K2; k2 += 2) {
        unsigned a00 = a0p[k2], a01 = a0p[k2 + 1];
        unsigned a10 = a1p[k2], a11 = a1p[k2 + 1];
        const uint4 w00 = *(const uint4*)(Wp + (size_t)k2 * 512 + n0);
        const uint4 w01 = *(const uint4*)(Wp + (size_t)k2 * 512 + n0 + 4);
        const uint4 w10 = *(const uint4*)(Wp + (size_t)(k2 + 1) * 512 + n0);
        const uint4 w11 = *(const uint4*)(Wp + (size_t)(k2 + 1) * 512 + n0 + 4);
        dot8(acc0, a00, w00, w01);
        dot8(acc1, a10, w00, w01);
        dot8(acc0, a01, w10, w11);
        dot8(acc1, a11, w10, w11);
    }

    float bv[8];
#pragma unroll
    for (int c = 0; c < 8; ++c) bv[c] = bias[n0 + c];

    float* Crow0 = C + (size_t)(m0 + rg * 2) * 512 + n0;
    float* Crow1 = Crow0 + 512;
    *(float4*)(Crow0)     = make_float4(acc0[0] + bv[0], acc0[1] + bv[1], acc0[2] + bv[2], acc0[3] + bv[3]);
    *(float4*)(Crow0 + 4) = make_float4(acc0[4] + bv[4], acc0[5] + bv[5], acc0[6] + bv[6], acc0[7] + bv[7]);
    *(float4*)(Crow1)     = make_float4(acc1[0] + bv[0], acc1[1] + bv[1], acc1[2] + bv[2], acc1[3] + bv[3]);
    *(float4*)(Crow1 + 4) = make_float4(acc1[4] + bv[4], acc1[5] + bv[5], acc1[6] + bv[6], acc1[7] + bv[7]);
}

// ---------------------------------------------------------------------------
// RNN scan v5b: ONE WG per batch element -> ZERO cross-WG communication
// (v3/v4 floored at ~3900 cyc/step = agent-atomic exchange RT; removed).
// 64 WGs x 512 thr (8 waves, 2/SIMD, <=256 VGPR).  Thread (w, rowsub, kg):
// 8 rows {w*64+rowsub+8j}, k-pairs [kg*32,+32) -> 256 fdot2/step.
// Weights: rows j=0..5 resident (192 VGPR/AGPR), rows j=6,7 in 128 KB LDS
// (q^rowsub swizzle -> max 2-way conflict on ds_read_b128).  h: f16 in
// swizzled LDS, read inline in the dot loop (4 live regs, not 32).
// kg-reduction: all-VALU butterfly (DPP ror8 + permlane16/32_swap) to keep
// the LDS pipe free for weight reads.  Every thread finalizes 1 row.
// One __syncthreads per step; parity-buffered h; t-loop unrolled x2 so
// buffer selection is static.
// ---------------------------------------------------------------------------
#define SMEM_SCAN_BYTES (128 * 1024 + 2 * HH * 2)   // Wl[128][64]u4 + hsh0/1[512]u16

__launch_bounds__(512, 2)
__global__ void rnn_scan5(const unsigned* __restrict__ Wq,   // [512][256] f16x2
                          const float* __restrict__ h0,      // [B][512]
                          float* __restrict__ states,        // [T][B][512] in:pre out:h
                          float* __restrict__ last) {        // [B][512]
    extern __shared__ char smem[];
    uint4* Wl = (uint4*)smem;                                     // [128 rows][64] swizzled
    unsigned short* hsh0 = (unsigned short*)(smem + 128 * 1024);  // [512]
    unsigned short* hsh1 = hsh0 + HH;                             // [512]

    const int b = blockIdx.x;
    const int tid = threadIdx.x;
    const int w = tid >> 6;
    const int lane = tid & 63;
    const int rowsub = lane & 7;
    const int kg = lane >> 3;
    const int rfin = w * 64 + rowsub + 8 * kg;   // the row this thread finalizes

    // --- resident weights: rows j=0..5, my kg chunk (48 uint4 = 192 regs) ---
    uint4 wreg[6][8];
#pragma unroll
    for (int j = 0; j < 6; ++j) {
        const uint4* Wr = (const uint4*)(Wq + (size_t)(w * 64 + rowsub + 8 * j) * 256) + kg * 8;
#pragma unroll
        for (int q = 0; q < 8; ++q) wreg[j][q] = Wr[q];
    }
    // --- LDS weights: rows j=6,7 (q XOR-swizzled by rowsub -> 2-way max) ---
#pragma unroll
    for (int j = 6; j < 8; ++j) {
        const uint4* Wr = (const uint4*)(Wq + (size_t)(w * 64 + rowsub + 8 * j) * 256) + kg * 8;
        const int rowLocal = w * 16 + (j - 6) * 8 + rowsub;   // 0..127
#pragma unroll
        for (int q = 0; q < 8; ++q)
            Wl[rowLocal * 64 + kg * 8 + (q ^ rowsub)] = Wr[q];
    }

    // --- stage h0 as f16 into hsh1 (buffer read at even t) ---
    hsh1[swz_us(tid)] = __half_as_ushort(__float2half_rn(h0[(size_t)b * HH + tid]));
    __syncthreads();

    const uint4* wbase = Wl + ((size_t)(w * 16 + rowsub) * 64 + kg * 8);
    const int hoff = kg * 8;                   // uint4 base of my h chunk
    const int wswz = swz_us(rfin);             // my h write slot (ushort idx)

    size_t base = (size_t)b * HH;
    const size_t tstride = (size_t)BB * HH;
    float pre_cur = states[base + rfin];
    float h = 0.f;

    const uint4* hbA = (const uint4*)hsh1;     // read at even t (h0 / odd-t writes)
    const uint4* hbB = (const uint4*)hsh0;     // read at odd t  (even-t writes)

    auto step = [&](const uint4* __restrict__ hbr, unsigned short* __restrict__ hshw, int t) {
        float pre_nxt = 0.f;
        if (t + 1 < TT) pre_nxt = states[base + tstride + rfin];   // prefetch

        float a0 = 0.f, a1 = 0.f, a2 = 0.f, a3 = 0.f;
        float a4 = 0.f, a5 = 0.f, a6 = 0.f, a7 = 0.f;
#pragma unroll
        for (int q = 0; q < 8; ++q) {
            const uint4 hq = hbr[hoff + (q ^ kg)];        // broadcast within kg-group
            const uint4 w6 = wbase[(q ^ rowsub)];
            const uint4 w7 = wbase[(q ^ rowsub) + 512];
            a0 = fdot2(wreg[0][q].x, hq.x, a0);
            a0 = fdot2(wreg[0][q].y, hq.y, a0);
            a0 = fdot2(wreg[0][q].z, hq.z, a0);
            a0 = fdot2(wreg[0][q].w, hq.w, a0);
            a1 = fdot2(wreg[1][q].x, hq.x, a1);
            a1 = fdot2(wreg[1][q].y, hq.y, a1);
            a1 = fdot2(wreg[1][q].z, hq.z, a1);
            a1 = fdot2(wreg[1][q].w, hq.w, a1);
            a2 = fdot2(wreg[2][q].x, hq.x, a2);
            a2 = fdot2(wreg[2][q].y, hq.y, a2);
            a2 = fdot2(wreg[2][q].z, hq.z, a2);
            a2 = fdot2(wreg[2][q].w, hq.w, a2);
            a3 = fdot2(wreg[3][q].x, hq.x, a3);
            a3 = fdot2(wreg[3][q].y, hq.y, a3);
            a3 = fdot2(wreg[3][q].z, hq.z, a3);
            a3 = fdot2(wreg[3][q].w, hq.w, a3);
            a4 = fdot2(wreg[4][q].x, hq.x, a4);
            a4 = fdot2(wreg[4][q].y, hq.y, a4);
            a4 = fdot2(wreg[4][q].z, hq.z, a4);
            a4 = fdot2(wreg[4][q].w, hq.w, a4);
            a5 = fdot2(wreg[5][q].x, hq.x, a5);
            a5 = fdot2(wreg[5][q].y, hq.y, a5);
            a5 = fdot2(wreg[5][q].z, hq.z, a5);
            a5 = fdot2(wreg[5][q].w, hq.w, a5);
            a6 = fdot2(w6.x, hq.x, a6);
            a6 = fdot2(w6.y, hq.y, a6);
            a6 = fdot2(w6.z, hq.z, a6);
            a6 = fdot2(w6.w, hq.w, a6);
            a7 = fdot2(w7.x, hq.x, a7);
            a7 = fdot2(w7.y, hq.y, a7);
            a7 = fdot2(w7.z, hq.z, a7);
            a7 = fdot2(w7.w, hq.w, a7);
        }
        // all-VALU kg-reduction (LDS pipe stays free for weight reads)
        a0 = bsum8(a0); a1 = bsum8(a1); a2 = bsum8(a2); a3 = bsum8(a3);
        a4 = bsum8(a4); a5 = bsum8(a5); a6 = bsum8(a6); a7 = bsum8(a7);

        // this thread finalizes row rfin (chain j == kg): static select
        float af = (kg == 0) ? a0 : (kg == 1) ? a1 : (kg == 2) ? a2 : (kg == 3) ? a3
                 : (kg == 4) ? a4 : (kg == 5) ? a5 : (kg == 6) ? a6 : a7;
        h = tanh_fast(pre_cur + af);
        states[base + rfin] = h;                           // full 256B/wave segment
        hshw[wswz] = __half_as_ushort(__float2half_rn(h));
        __syncthreads();

        pre_cur = pre_nxt;
        base += tstride;
    };

    for (int t = 0; t < TT; t += 2) {
        step(hbA, hsh0, t);        // even t: read h(t-1) from hsh1, write h(t) -> hsh0
        step(hbB, hsh1, t + 1);    // odd  t: read from hsh0, write -> hsh1
    }

    last[(size_t)b * HH + rfin] = h;
}

// ---------------------------------------------------------------------------
// FALLBACK (round-2, known-passing): 2 WGs/batch row-split with tagged-u64
// agent-atomic exchange.  Used only if the >64KB-dynamic-LDS path is
// unavailable on this runtime.
// ---------------------------------------------------------------------------
__launch_bounds__(512, 1)
__global__ void rnn_scan4(const unsigned* __restrict__ Wq,   // [512][256] f16x2
                          const float* __restrict__ h0,      // [B][512]
                          float* __restrict__ states,        // [T][B][512] in:pre out:h
                          float* __restrict__ last,          // [B][512]
                          unsigned long long* __restrict__ X) { // [B][2 side][2 par][256]
    __shared__ unsigned short hsh[2][512];   // full h as f16, parity-buffered

    const int wg = blockIdx.x;
    const int b = wg & 63;
    const int s = wg >> 6;
    const int tid = threadIdx.x;
    const int w = tid >> 6;
    const int lane = tid & 63;
    const int rowsub = lane & 7;
    const int kg = lane >> 3;
    const int rbase = s * 256 + w * 32 + rowsub;
    const bool is_fin = (kg < 4);
    const int rfin = rbase + 8 * kg;
    const int fidx = w * 32 + rowsub + 8 * kg;
    const int pidx = w * 32 + (lane & 31);
    const int rpoll = (1 - s) * 256 + pidx;

    uint4 wreg[4][8];
#pragma unroll
    for (int j = 0; j < 4; ++j) {
        const uint4* Wr = (const uint4*)(Wq + (size_t)(rbase + 8 * j) * 256 + kg * 32);
#pragma unroll
        for (int q = 0; q < 8; ++q) wreg[j][q] = Wr[q];
    }

    hsh[1][swz_us(tid)] = __half_as_ushort(__float2half_rn(h0[(size_t)b * HH + tid]));
    __syncthreads();
    uint4 hv[8];
    {
        const uint4* hb = (const uint4*)hsh[1];
#pragma unroll
        for (int q = 0; q < 8; ++q) hv[q] = hb[kg * 8 + (q ^ kg)];
    }

    unsigned long long* slotW_A = X + (((size_t)(b * 2 + s) * 2 + 0) << 8) + fidx;
    unsigned long long* slotW_B = slotW_A + 256;
    unsigned long long* slotR_A = X + (((size_t)(b * 2 + (1 - s)) * 2 + 0) << 8) + pidx;
    unsigned long long* slotR_B = slotR_A + 256;

    size_t base = (size_t)b * HH;
    const size_t tstride = (size_t)BB * HH;

    float pre_cur = 0.f;
    if (is_fin) pre_cur = states[base + rfin];

    float hlast = 0.f;
    for (int t = 0; t < TT; ++t) {
        float pre_nxt = 0.f;
        if (is_fin && t + 1 < TT) pre_nxt = states[base + tstride + rfin];

        float a0 = 0.f, a1 = 0.f, a2 = 0.f, a3 = 0.f;
#pragma unroll
        for (int q = 0; q < 8; ++q) {
            const uint4 hq = hv[q];
            a0 = fdot2(wreg[0][q].x, hq.x, a0);
            a0 = fdot2(wreg[0][q].y, hq.y, a0);
            a0 = fdot2(wreg[0][q].z, hq.z, a0);
            a0 = fdot2(wreg[0][q].w, hq.w, a0);
            a1 = fdot2(wreg[1][q].x, hq.x, a1);
            a1 = fdot2(wreg[1][q].y, hq.y, a1);
            a1 = fdot2(wreg[1][q].z, hq.z, a1);
            a1 = fdot2(wreg[1][q].w, hq.w, a1);
            a2 = fdot2(wreg[2][q].x, hq.x, a2);
            a2 = fdot2(wreg[2][q].y, hq.y, a2);
            a2 = fdot2(wreg[2][q].z, hq.z, a2);
            a2 = fdot2(wreg[2][q].w, hq.w, a2);
            a3 = fdot2(wreg[3][q].x, hq.x, a3);
            a3 = fdot2(wreg[3][q].y, hq.y, a3);
            a3 = fdot2(wreg[3][q].z, hq.z, a3);
            a3 = fdot2(wreg[3][q].w, hq.w, a3);
        }
        a0 += __shfl_xor(a0, 8);  a0 += __shfl_xor(a0, 16);  a0 += __shfl_xor(a0, 32);
        a1 += __shfl_xor(a1, 8);  a1 += __shfl_xor(a1, 16);  a1 += __shfl_xor(a1, 32);
        a2 += __shfl_xor(a2, 8);  a2 += __shfl_xor(a2, 16);  a2 += __shfl_xor(a2, 32);
        a3 += __shfl_xor(a3, 8);  a3 += __shfl_xor(a3, 16);  a3 += __shfl_xor(a3, 32);

        const int p = t & 1;
        if (is_fin) {
            float af = (kg == 0) ? a0 : (kg == 1) ? a1 : (kg == 2) ? a2 : a3;
            float hh = tanh_fast(pre_cur + af);
            hlast = hh;
            states[base + rfin] = hh;
            unsigned long long msg = ((unsigned long long)(unsigned)(t + 1) << 32)
                                   | (unsigned long long)__float_as_uint(hh);
            __hip_atomic_store(p ? slotW_B : slotW_A, msg, __ATOMIC_RELAXED, AGENT);
            hsh[p][swz_us(rfin)] = __half_as_ushort(__float2half_rn(hh));
        } else {
            unsigned long long* slot = p ? slotR_B : slotR_A;
            unsigned long long v;
            do {
                v = __hip_atomic_load(slot, __ATOMIC_RELAXED, AGENT);
            } while ((unsigned)(v >> 32) != (unsigned)(t + 1));
            float hp_ = __uint_as_float((unsigned)v);
            hsh[p][swz_us(rpoll)] = __half_as_ushort(__float2half_rn(hp_));
        }
        __syncthreads();

        const uint4* hb = (const uint4*)hsh[p];
#pragma unroll
        for (int q = 0; q < 8; ++q) hv[q] = hb[kg * 8 + (q ^ kg)];

        pre_cur = pre_nxt;
        base += tstride;
    }

    if (is_fin) last[(size_t)b * HH + rfin] = hlast;
}

// ---------------------------------------------------------------------------
extern "C" void kernel_launch(void* const* d_in, const int* in_sizes, int n_in,
                              void* d_out, int out_size, void* d_ws, size_t ws_size,
                              hipStream_t stream) {
    (void)in_sizes; (void)n_in; (void)out_size; (void)ws_size;
    const float* inputs = (const float*)d_in[0];   // (T,B,V)
    const float* H      = (const float*)d_in[1];   // (L,B,HID)
    const float* Wnet   = (const float*)d_in[2];   // (HID, V+HID)
    const float* bnet   = (const float*)d_in[3];   // (HID,)
    const float* Wdeep  = (const float*)d_in[4];   // (HID, 2*HID)
    const float* bdeep  = (const float*)d_in[5];   // (HID,)
    float* out = (float*)d_out;

    // workspace layout (X first for 8B alignment); ~2.3 MB total
    unsigned long long* X = (unsigned long long*)d_ws;  // 64*2*2*256 u64 = 512 KB
    unsigned* Wq0 = (unsigned*)(X + 64 * 2 * 2 * 256);  // 131072 u32
    unsigned* Wq1 = Wq0 + HH * (HH / 2);                // 131072 u32
    unsigned* Wp0 = Wq1 + HH * (HH / 2);                // 65536 u32
    unsigned* Wp1 = Wp0 + (VV / 2) * HH;                // 131072 u32

    // Big-LDS opt-in, verified; choose scan path once (host-only queries,
    // graph-capture safe: no allocation/sync/stream ops).
    static int scan5_ok = -1;
    if (scan5_ok < 0) {
        hipError_t e1 = hipFuncSetAttribute((const void*)rnn_scan5,
                                            hipFuncAttributeMaxDynamicSharedMemorySize,
                                            SMEM_SCAN_BYTES);
        hipFuncAttributes fa;
        hipError_t e2 = hipFuncGetAttributes(&fa, (const void*)rnn_scan5);
        scan5_ok = (e1 == hipSuccess && e2 == hipSuccess &&
                    fa.maxDynamicSharedSizeBytes >= (int)SMEM_SCAN_BYTES) ? 1 : 0;
    }

    // 1) pack weights (458752 ids / 256 = 1792 blocks)
    hipLaunchKernelGGL(pack_weights, dim3(1792), dim3(256), 0, stream,
                       Wnet, Wdeep, Wq0, Wq1, Wp0, Wp1);

    // 2) pre0 = inputs @ Wx0^T + b_net  -> d_out[0:TBH]
    hipLaunchKernelGGL(xproj_f16, dim3((TT * BB) / 32), dim3(1024),
                       32 * (VV / 2) * sizeof(unsigned), stream,
                       inputs, Wp0, bnet, out, VV);

    // 3) layer-0 scan
    if (scan5_ok) {
        hipLaunchKernelGGL(rnn_scan5, dim3(64), dim3(512), SMEM_SCAN_BYTES, stream,
                           Wq0, H, out, out + TBH);
    } else {
        hipLaunchKernelGGL(rnn_scan4, dim3(128), dim3(512), 0, stream,
                           Wq0, H, out, out + TBH, X);
    }

    // 4) pre1 = states0 @ Wx1^T + b_deep (in-place over d_out)
    hipLaunchKernelGGL(xproj_f16, dim3((TT * BB) / 32), dim3(1024),
                       32 * (HH / 2) * sizeof(unsigned), stream,
                       out, Wp1, bdeep, out, HH);

    // 5) layer-1 scan
    if (scan5_ok) {
        hipLaunchKernelGGL(rnn_scan5, dim3(64), dim3(512), SMEM_SCAN_BYTES, stream,
                           Wq1, H + (size_t)BB * HH, out, out + TBH + (size_t)BB * HH);
    } else {
        hipLaunchKernelGGL(rnn_scan4, dim3(128), dim3(512), 0, stream,
                           Wq1, H + (size_t)BB * HH, out, out + TBH + (size_t)BB * HH, X);
    }
}

// Round 5
// 4152.699 us; speedup vs baseline: 1.0242x; 1.0017x over previous
//
#include <hip/hip_runtime.h>
#include <hip/hip_fp16.h>
#include <cstdint>
#include <cstddef>

// Problem constants (T, B, V, HID, L) from the reference.
#define TT 1024
#define BB 64
#define VV 256
#define HH 512
static const size_t TBH = (size_t)TT * BB * HH;   // 33,554,432 floats

#define AGENT __HIP_MEMORY_SCOPE_AGENT

typedef _Float16 half2v __attribute__((ext_vector_type(2)));
union U32H2 { unsigned u; half2v h; };

__device__ __forceinline__ unsigned pack_f16x2(float a, float b) {
    __half ha = __float2half_rn(a);
    __half hb = __float2half_rn(b);
    return (unsigned)__half_as_ushort(ha) | ((unsigned)__half_as_ushort(hb) << 16);
}

__device__ __forceinline__ float tanh_fast(float x) {
    // tanh(x) = sign(x) * (1 - e^-2|x|) / (1 + e^-2|x|)
    float ax = fabsf(x);
    float e = __expf(-2.0f * ax);
    float r = (1.0f - e) * __builtin_amdgcn_rcpf(1.0f + e);
    return copysignf(r, x);
}

__device__ __forceinline__ float fdot2(unsigned w, unsigned h, float acc) {
    U32H2 uw; uw.u = w;
    U32H2 uh; uh.u = h;
#if __has_builtin(__builtin_amdgcn_fdot2)
    return __builtin_amdgcn_fdot2(uw.h, uh.h, acc, false);
#else
    return acc + (float)uw.h[0] * (float)uh.h[0] + (float)uw.h[1] * (float)uh.h[1];
#endif
}

// h-LDS swizzle: pair j (dword) lives at dword index j ^ (((j>>5)&7)<<2).
// Involution; preserves uint4 groups (XOR is a multiple of 4 dwords). A
// wave's uint4 read at fixed q across kg=0..7 hits bank-quads (q^kg) -- all
// distinct -> conflict-free; the 8 lanes sharing kg broadcast (same addr).
__device__ __forceinline__ int swz_us(int r) {     // row -> ushort index
    int j = r >> 1;
    int js = j ^ (((j >> 5) & 7) << 2);
    return (js << 1) | (r & 1);
}

// All-VALU butterfly sum over lane bits 3..5 (the kg dimension): keeps the
// reduction OFF the LDS pipe (which carries weight/h ds_read_b128).
//  lane^8 : DPP row_ror:8 (rotation within each 16-lane row == xor 8)
//  lane^16: gfx950 v_permlane16_swap; lane^32: v_permlane32_swap.
// permlaneN_swap(x, x) returns {a,b} with a[l]+b[l] == x[l] + x[l^N].
__device__ __forceinline__ float bsum8(float v) {
    int d = __builtin_amdgcn_update_dpp(0, __float_as_int(v), 0x128, 0xF, 0xF, true);
    v += __int_as_float(d);
#if __has_builtin(__builtin_amdgcn_permlane16_swap) && __has_builtin(__builtin_amdgcn_permlane32_swap)
    {
        auto r1 = __builtin_amdgcn_permlane16_swap(__float_as_uint(v), __float_as_uint(v), false, false);
        v = __uint_as_float(r1[0]) + __uint_as_float(r1[1]);
        auto r2 = __builtin_amdgcn_permlane32_swap(__float_as_uint(v), __float_as_uint(v), false, false);
        v = __uint_as_float(r2[0]) + __uint_as_float(r2[1]);
    }
#else
    int l = (int)(threadIdx.x & 63);
    v += __int_as_float(__builtin_amdgcn_ds_bpermute((l ^ 16) << 2, __float_as_int(v)));
    v += __int_as_float(__builtin_amdgcn_ds_bpermute((l ^ 32) << 2, __float_as_int(v)));
#endif
    return v;
}

// ---------------------------------------------------------------------------
// Weight prep:
//  Wq0/Wq1 : recurrent Wh rows as f16x2 k-pairs   [512 rows][256 pairs]
//  Wp0/Wp1 : input-proj Wx^T as f16x2 k-pairs     [K/2 pairs][512 cols]
// ---------------------------------------------------------------------------
__global__ void pack_weights(const float* __restrict__ Wnet,
                             const float* __restrict__ Wdeep,
                             unsigned* __restrict__ Wq0, unsigned* __restrict__ Wq1,
                             unsigned* __restrict__ Wp0, unsigned* __restrict__ Wp1) {
    int id = blockIdx.x * 256 + threadIdx.x;
    const int NQ  = HH * (HH / 2);     // 131072
    const int NP0 = (VV / 2) * HH;     // 65536
    const int NP1 = (HH / 2) * HH;     // 131072
    if (id < NQ) {
        int i = id >> 8, jp = id & 255;
        const float* row = Wnet + (size_t)i * (VV + HH) + VV;   // Wh0[i][:]
        Wq0[id] = pack_f16x2(row[2 * jp], row[2 * jp + 1]);
        return;
    }
    id -= NQ;
    if (id < NQ) {
        int i = id >> 8, jp = id & 255;
        const float* row = Wdeep + (size_t)i * (2 * HH) + HH;   // Wh1[i][:]
        Wq1[id] = pack_f16x2(row[2 * jp], row[2 * jp + 1]);
        return;
    }
    id -= NQ;
    if (id < NP0) {
        int k2 = id >> 9, n = id & 511;                          // Wx0[n][2k2..]
        const float* row = Wnet + (size_t)n * (VV + HH);
        Wp0[id] = pack_f16x2(row[2 * k2], row[2 * k2 + 1]);
        return;
    }
    id -= NP0;
    if (id < NP1) {
        int k2 = id >> 9, n = id & 511;                          // Wx1[n][2k2..]
        const float* row = Wdeep + (size_t)n * (2 * HH);
        Wp1[id] = pack_f16x2(row[2 * k2], row[2 * k2 + 1]);
        return;
    }
}

// ---------------------------------------------------------------------------
// Input-projection GEMM (f16 dot2): C[M,512] = A[M,K] @ Wx^T + bias.
// ---------------------------------------------------------------------------
__device__ __forceinline__ void dot8(float* acc, unsigned a, uint4 w0, uint4 w1) {
    acc[0] = fdot2(w0.x, a, acc[0]);
    acc[1] = fdot2(w0.y, a, acc[1]);
    acc[2] = fdot2(w0.z, a, acc[2]);
    acc[3] = fdot2(w0.w, a, acc[3]);
    acc[4] = fdot2(w1.x, a, acc[4]);
    acc[5] = fdot2(w1.y, a, acc[5]);
    acc[6] = fdot2(w1.z, a, acc[6]);
    acc[7] = fdot2(w1.w, a, acc[7]);
}

__launch_bounds__(1024)
__global__ void xproj_f16(const float* __restrict__ A,
                          const unsigned* __restrict__ Wp,   // [K/2][512] f16x2
                          const float* __restrict__ bias,
                          float* __restrict__ C, int K) {
    extern __shared__ unsigned As2[];      // 32 rows * K/2 pairs
    const int m0 = blockIdx.x * 32;
    const int t = threadIdx.x;
    const int K2 = K >> 1;

    const int nf4 = 8 * K;                 // 32*K/4
    const float4* Ag = (const float4*)(A + (size_t)m0 * K);
    for (int idx = t; idx < nf4; idx += 1024) {
        float4 v = Ag[idx];
        As2[idx * 2]     = pack_f16x2(v.x, v.y);
        As2[idx * 2 + 1] = pack_f16x2(v.z, v.w);
    }
    __syncthreads();

    const int rg = t >> 6;                 // 2 rows per thread
    const int n0 = (t & 63) * 8;

    float acc0[8] = {0, 0, 0, 0, 0, 0, 0, 0};
    float acc1[8] = {0, 0, 0, 0, 0, 0, 0, 0};

    const unsigned* a0p = As2 + (size_t)(rg * 2) * K2;
    const unsigned* a1p = a0p + K2;

#pragma unroll 4
    for (int k2 = 0; k2 < K2; k2 += 2) {
        unsigned a00 = a0p[k2], a01 = a0p[k2 + 1];
        unsigned a10 = a1p[k2], a11 = a1p[k2 + 1];
        const uint4 w00 = *(const uint4*)(Wp + (size_t)k2 * 512 + n0);
        const uint4 w01 = *(const uint4*)(Wp + (size_t)k2 * 512 + n0 + 4);
        const uint4 w10 = *(const uint4*)(Wp + (size_t)(k2 + 1) * 512 + n0);
        const uint4 w11 = *(const uint4*)(Wp + (size_t)(k2 + 1) * 512 + n0 + 4);
        dot8(acc0, a00, w00, w01);
        dot8(acc1, a10, w00, w01);
        dot8(acc0, a01, w10, w11);
        dot8(acc1, a11, w10, w11);
    }

    float bv[8];
#pragma unroll
    for (int c = 0; c < 8; ++c) bv[c] = bias[n0 + c];

    float* Crow0 = C + (size_t)(m0 + rg * 2) * 512 + n0;
    float* Crow1 = Crow0 + 512;
    *(float4*)(Crow0)     = make_float4(acc0[0] + bv[0], acc0[1] + bv[1], acc0[2] + bv[2], acc0[3] + bv[3]);
    *(float4*)(Crow0 + 4) = make_float4(acc0[4] + bv[4], acc0[5] + bv[5], acc0[6] + bv[6], acc0[7] + bv[7]);
    *(float4*)(Crow1)     = make_float4(acc1[0] + bv[0], acc1[1] + bv[1], acc1[2] + bv[2], acc1[3] + bv[3]);
    *(float4*)(Crow1 + 4) = make_float4(acc1[4] + bv[4], acc1[5] + bv[5], acc1[6] + bv[6], acc1[7] + bv[7]);
}

// ---------------------------------------------------------------------------
// RNN scan v6: v5 structure (one WG per batch, zero cross-WG traffic) with
// the barrier drain removed.  v3/v4/v5 post-mortem: ALL structures floored
// at ~3880 cyc/step because __syncthreads makes hipcc emit
// `s_waitcnt vmcnt(0) expcnt(0) lgkmcnt(0)` before s_barrier (guide §5/m97),
// so every step serialized on the h global-store drain AND the pre_nxt
// "prefetch" load (FETCH shows ~half from HBM: ~400-900 cyc/step).
// Fix (T4 counted-wait): LDS h visibility only needs lgkmcnt(0) -> raw
// s_barrier with an inline-asm lgkmcnt wait; the global store and the
// pre-load stay in flight across the barrier (consumed a full step later).
// Also __launch_bounds__(512) [was (512,2)]: lets the allocator use 256
// arch VGPRs (was split 128 arch + AGPR -> accvgpr_read moves per weight
// use); occupancy is LDS-limited to 1 WG/CU regardless.
// ---------------------------------------------------------------------------
#define SMEM_SCAN_BYTES (128 * 1024 + 2 * HH * 2)   // Wl[128][64]u4 + hsh0/1[512]u16

__launch_bounds__(512)
__global__ void rnn_scan5(const unsigned* __restrict__ Wq,   // [512][256] f16x2
                          const float* __restrict__ h0,      // [B][512]
                          float* __restrict__ states,        // [T][B][512] in:pre out:h
                          float* __restrict__ last) {        // [B][512]
    extern __shared__ char smem[];
    uint4* Wl = (uint4*)smem;                                     // [128 rows][64] swizzled
    unsigned short* hsh0 = (unsigned short*)(smem + 128 * 1024);  // [512]
    unsigned short* hsh1 = hsh0 + HH;                             // [512]

    const int b = blockIdx.x;
    const int tid = threadIdx.x;
    const int w = tid >> 6;
    const int lane = tid & 63;
    const int rowsub = lane & 7;
    const int kg = lane >> 3;
    const int rfin = w * 64 + rowsub + 8 * kg;   // the row this thread finalizes

    // --- resident weights: rows j=0..5, my kg chunk (48 uint4 = 192 regs) ---
    uint4 wreg[6][8];
#pragma unroll
    for (int j = 0; j < 6; ++j) {
        const uint4* Wr = (const uint4*)(Wq + (size_t)(w * 64 + rowsub + 8 * j) * 256) + kg * 8;
#pragma unroll
        for (int q = 0; q < 8; ++q) wreg[j][q] = Wr[q];
    }
    // --- LDS weights: rows j=6,7 (q XOR-swizzled by rowsub -> 2-way max) ---
#pragma unroll
    for (int j = 6; j < 8; ++j) {
        const uint4* Wr = (const uint4*)(Wq + (size_t)(w * 64 + rowsub + 8 * j) * 256) + kg * 8;
        const int rowLocal = w * 16 + (j - 6) * 8 + rowsub;   // 0..127
#pragma unroll
        for (int q = 0; q < 8; ++q)
            Wl[rowLocal * 64 + kg * 8 + (q ^ rowsub)] = Wr[q];
    }

    // --- stage h0 as f16 into hsh1 (buffer read at even t) ---
    hsh1[swz_us(tid)] = __half_as_ushort(__float2half_rn(h0[(size_t)b * HH + tid]));
    __syncthreads();   // once; full drain here is fine

    const uint4* wbase = Wl + ((size_t)(w * 16 + rowsub) * 64 + kg * 8);
    const int hoff = kg * 8;                   // uint4 base of my h chunk
    const int wswz = swz_us(rfin);             // my h write slot (ushort idx)

    size_t base = (size_t)b * HH;
    const size_t tstride = (size_t)BB * HH;
    float pre_cur = states[base + rfin];
    float h = 0.f;

    const uint4* hbA = (const uint4*)hsh1;     // read at even t (h0 / odd-t writes)
    const uint4* hbB = (const uint4*)hsh0;     // read at odd t  (even-t writes)

    auto step = [&](const uint4* __restrict__ hbr, unsigned short* __restrict__ hshw, int t) {
        float pre_nxt = 0.f;
        if (t + 1 < TT) pre_nxt = states[base + tstride + rfin];   // stays in flight across barrier

        float a0 = 0.f, a1 = 0.f, a2 = 0.f, a3 = 0.f;
        float a4 = 0.f, a5 = 0.f, a6 = 0.f, a7 = 0.f;
#pragma unroll
        for (int q = 0; q < 8; ++q) {
            const uint4 hq = hbr[hoff + (q ^ kg)];        // broadcast within kg-group
            const uint4 w6 = wbase[(q ^ rowsub)];
            const uint4 w7 = wbase[(q ^ rowsub) + 512];
            a0 = fdot2(wreg[0][q].x, hq.x, a0);
            a0 = fdot2(wreg[0][q].y, hq.y, a0);
            a0 = fdot2(wreg[0][q].z, hq.z, a0);
            a0 = fdot2(wreg[0][q].w, hq.w, a0);
            a1 = fdot2(wreg[1][q].x, hq.x, a1);
            a1 = fdot2(wreg[1][q].y, hq.y, a1);
            a1 = fdot2(wreg[1][q].z, hq.z, a1);
            a1 = fdot2(wreg[1][q].w, hq.w, a1);
            a2 = fdot2(wreg[2][q].x, hq.x, a2);
            a2 = fdot2(wreg[2][q].y, hq.y, a2);
            a2 = fdot2(wreg[2][q].z, hq.z, a2);
            a2 = fdot2(wreg[2][q].w, hq.w, a2);
            a3 = fdot2(wreg[3][q].x, hq.x, a3);
            a3 = fdot2(wreg[3][q].y, hq.y, a3);
            a3 = fdot2(wreg[3][q].z, hq.z, a3);
            a3 = fdot2(wreg[3][q].w, hq.w, a3);
            a4 = fdot2(wreg[4][q].x, hq.x, a4);
            a4 = fdot2(wreg[4][q].y, hq.y, a4);
            a4 = fdot2(wreg[4][q].z, hq.z, a4);
            a4 = fdot2(wreg[4][q].w, hq.w, a4);
            a5 = fdot2(wreg[5][q].x, hq.x, a5);
            a5 = fdot2(wreg[5][q].y, hq.y, a5);
            a5 = fdot2(wreg[5][q].z, hq.z, a5);
            a5 = fdot2(wreg[5][q].w, hq.w, a5);
            a6 = fdot2(w6.x, hq.x, a6);
            a6 = fdot2(w6.y, hq.y, a6);
            a6 = fdot2(w6.z, hq.z, a6);
            a6 = fdot2(w6.w, hq.w, a6);
            a7 = fdot2(w7.x, hq.x, a7);
            a7 = fdot2(w7.y, hq.y, a7);
            a7 = fdot2(w7.z, hq.z, a7);
            a7 = fdot2(w7.w, hq.w, a7);
        }
        // all-VALU kg-reduction (LDS pipe stays free for weight reads)
        a0 = bsum8(a0); a1 = bsum8(a1); a2 = bsum8(a2); a3 = bsum8(a3);
        a4 = bsum8(a4); a5 = bsum8(a5); a6 = bsum8(a6); a7 = bsum8(a7);

        // this thread finalizes row rfin (chain j == kg): static select
        float af = (kg == 0) ? a0 : (kg == 1) ? a1 : (kg == 2) ? a2 : (kg == 3) ? a3
                 : (kg == 4) ? a4 : (kg == 5) ? a5 : (kg == 6) ? a6 : a7;
        h = tanh_fast(pre_cur + af);
        states[base + rfin] = h;               // fire-and-forget (never drained in-loop)
        hshw[wswz] = __half_as_ushort(__float2half_rn(h));

        // Counted-wait barrier (T4): only LDS must be visible across waves.
        // NO vmcnt drain -- the h store and pre_nxt load stay in flight.
        asm volatile("s_waitcnt lgkmcnt(0)" ::: "memory");
        __builtin_amdgcn_s_barrier();
        __builtin_amdgcn_sched_barrier(0);     // rule #18: pin reads after barrier

        pre_cur = pre_nxt;
        base += tstride;
    };

    for (int t = 0; t < TT; t += 2) {
        step(hbA, hsh0, t);        // even t: read h(t-1) from hsh1, write h(t) -> hsh0
        step(hbB, hsh1, t + 1);    // odd  t: read from hsh0, write -> hsh1
    }

    last[(size_t)b * HH + rfin] = h;
}

// ---------------------------------------------------------------------------
// FALLBACK (round-2, known-passing): 2 WGs/batch row-split with tagged-u64
// agent-atomic exchange.  Used only if the >64KB-dynamic-LDS path is
// unavailable on this runtime.
// ---------------------------------------------------------------------------
__launch_bounds__(512, 1)
__global__ void rnn_scan4(const unsigned* __restrict__ Wq,   // [512][256] f16x2
                          const float* __restrict__ h0,      // [B][512]
                          float* __restrict__ states,        // [T][B][512] in:pre out:h
                          float* __restrict__ last,          // [B][512]
                          unsigned long long* __restrict__ X) { // [B][2 side][2 par][256]
    __shared__ unsigned short hsh[2][512];   // full h as f16, parity-buffered

    const int wg = blockIdx.x;
    const int b = wg & 63;
    const int s = wg >> 6;
    const int tid = threadIdx.x;
    const int w = tid >> 6;
    const int lane = tid & 63;
    const int rowsub = lane & 7;
    const int kg = lane >> 3;
    const int rbase = s * 256 + w * 32 + rowsub;
    const bool is_fin = (kg < 4);
    const int rfin = rbase + 8 * kg;
    const int fidx = w * 32 + rowsub + 8 * kg;
    const int pidx = w * 32 + (lane & 31);
    const int rpoll = (1 - s) * 256 + pidx;

    uint4 wreg[4][8];
#pragma unroll
    for (int j = 0; j < 4; ++j) {
        const uint4* Wr = (const uint4*)(Wq + (size_t)(rbase + 8 * j) * 256 + kg * 32);
#pragma unroll
        for (int q = 0; q < 8; ++q) wreg[j][q] = Wr[q];
    }

    hsh[1][swz_us(tid)] = __half_as_ushort(__float2half_rn(h0[(size_t)b * HH + tid]));
    __syncthreads();
    uint4 hv[8];
    {
        const uint4* hb = (const uint4*)hsh[1];
#pragma unroll
        for (int q = 0; q < 8; ++q) hv[q] = hb[kg * 8 + (q ^ kg)];
    }

    unsigned long long* slotW_A = X + (((size_t)(b * 2 + s) * 2 + 0) << 8) + fidx;
    unsigned long long* slotW_B = slotW_A + 256;
    unsigned long long* slotR_A = X + (((size_t)(b * 2 + (1 - s)) * 2 + 0) << 8) + pidx;
    unsigned long long* slotR_B = slotR_A + 256;

    size_t base = (size_t)b * HH;
    const size_t tstride = (size_t)BB * HH;

    float pre_cur = 0.f;
    if (is_fin) pre_cur = states[base + rfin];

    float hlast = 0.f;
    for (int t = 0; t < TT; ++t) {
        float pre_nxt = 0.f;
        if (is_fin && t + 1 < TT) pre_nxt = states[base + tstride + rfin];

        float a0 = 0.f, a1 = 0.f, a2 = 0.f, a3 = 0.f;
#pragma unroll
        for (int q = 0; q < 8; ++q) {
            const uint4 hq = hv[q];
            a0 = fdot2(wreg[0][q].x, hq.x, a0);
            a0 = fdot2(wreg[0][q].y, hq.y, a0);
            a0 = fdot2(wreg[0][q].z, hq.z, a0);
            a0 = fdot2(wreg[0][q].w, hq.w, a0);
            a1 = fdot2(wreg[1][q].x, hq.x, a1);
            a1 = fdot2(wreg[1][q].y, hq.y, a1);
            a1 = fdot2(wreg[1][q].z, hq.z, a1);
            a1 = fdot2(wreg[1][q].w, hq.w, a1);
            a2 = fdot2(wreg[2][q].x, hq.x, a2);
            a2 = fdot2(wreg[2][q].y, hq.y, a2);
            a2 = fdot2(wreg[2][q].z, hq.z, a2);
            a2 = fdot2(wreg[2][q].w, hq.w, a2);
            a3 = fdot2(wreg[3][q].x, hq.x, a3);
            a3 = fdot2(wreg[3][q].y, hq.y, a3);
            a3 = fdot2(wreg[3][q].z, hq.z, a3);
            a3 = fdot2(wreg[3][q].w, hq.w, a3);
        }
        a0 += __shfl_xor(a0, 8);  a0 += __shfl_xor(a0, 16);  a0 += __shfl_xor(a0, 32);
        a1 += __shfl_xor(a1, 8);  a1 += __shfl_xor(a1, 16);  a1 += __shfl_xor(a1, 32);
        a2 += __shfl_xor(a2, 8);  a2 += __shfl_xor(a2, 16);  a2 += __shfl_xor(a2, 32);
        a3 += __shfl_xor(a3, 8);  a3 += __shfl_xor(a3, 16);  a3 += __shfl_xor(a3, 32);

        const int p = t & 1;
        if (is_fin) {
            float af = (kg == 0) ? a0 : (kg == 1) ? a1 : (kg == 2) ? a2 : a3;
            float hh = tanh_fast(pre_cur + af);
            hlast = hh;
            states[base + rfin] = hh;
            unsigned long long msg = ((unsigned long long)(unsigned)(t + 1) << 32)
                                   | (unsigned long long)__float_as_uint(hh);
            __hip_atomic_store(p ? slotW_B : slotW_A, msg, __ATOMIC_RELAXED, AGENT);
            hsh[p][swz_us(rfin)] = __half_as_ushort(__float2half_rn(hh));
        } else {
            unsigned long long* slot = p ? slotR_B : slotR_A;
            unsigned long long v;
            do {
                v = __hip_atomic_load(slot, __ATOMIC_RELAXED, AGENT);
            } while ((unsigned)(v >> 32) != (unsigned)(t + 1));
            float hp_ = __uint_as_float((unsigned)v);
            hsh[p][swz_us(rpoll)] = __half_as_ushort(__float2half_rn(hp_));
        }
        __syncthreads();

        const uint4* hb = (const uint4*)hsh[p];
#pragma unroll
        for (int q = 0; q < 8; ++q) hv[q] = hb[kg * 8 + (q ^ kg)];

        pre_cur = pre_nxt;
        base += tstride;
    }

    if (is_fin) last[(size_t)b * HH + rfin] = hlast;
}

// ---------------------------------------------------------------------------
extern "C" void kernel_launch(void* const* d_in, const int* in_sizes, int n_in,
                              void* d_out, int out_size, void* d_ws, size_t ws_size,
                              hipStream_t stream) {
    (void)in_sizes; (void)n_in; (void)out_size; (void)ws_size;
    const float* inputs = (const float*)d_in[0];   // (T,B,V)
    const float* H      = (const float*)d_in[1];   // (L,B,HID)
    const float* Wnet   = (const float*)d_in[2];   // (HID, V+HID)
    const float* bnet   = (const float*)d_in[3];   // (HID,)
    const float* Wdeep  = (const float*)d_in[4];   // (HID, 2*HID)
    const float* bdeep  = (const float*)d_in[5];   // (HID,)
    float* out = (float*)d_out;

    // workspace layout (X first for 8B alignment); ~2.3 MB total
    unsigned long long* X = (unsigned long long*)d_ws;  // 64*2*2*256 u64 = 512 KB
    unsigned* Wq0 = (unsigned*)(X + 64 * 2 * 2 * 256);  // 131072 u32
    unsigned* Wq1 = Wq0 + HH * (HH / 2);                // 131072 u32
    unsigned* Wp0 = Wq1 + HH * (HH / 2);                // 65536 u32
    unsigned* Wp1 = Wp0 + (VV / 2) * HH;                // 131072 u32

    // Big-LDS opt-in, verified; choose scan path once (host-only queries,
    // graph-capture safe: no allocation/sync/stream ops).
    static int scan5_ok = -1;
    if (scan5_ok < 0) {
        hipError_t e1 = hipFuncSetAttribute((const void*)rnn_scan5,
                                            hipFuncAttributeMaxDynamicSharedMemorySize,
                                            SMEM_SCAN_BYTES);
        hipFuncAttributes fa;
        hipError_t e2 = hipFuncGetAttributes(&fa, (const void*)rnn_scan5);
        scan5_ok = (e1 == hipSuccess && e2 == hipSuccess &&
                    fa.maxDynamicSharedSizeBytes >= (int)SMEM_SCAN_BYTES) ? 1 : 0;
    }

    // 1) pack weights (458752 ids / 256 = 1792 blocks)
    hipLaunchKernelGGL(pack_weights, dim3(1792), dim3(256), 0, stream,
                       Wnet, Wdeep, Wq0, Wq1, Wp0, Wp1);

    // 2) pre0 = inputs @ Wx0^T + b_net  -> d_out[0:TBH]
    hipLaunchKernelGGL(xproj_f16, dim3((TT * BB) / 32), dim3(1024),
                       32 * (VV / 2) * sizeof(unsigned), stream,
                       inputs, Wp0, bnet, out, VV);

    // 3) layer-0 scan
    if (scan5_ok) {
        hipLaunchKernelGGL(rnn_scan5, dim3(64), dim3(512), SMEM_SCAN_BYTES, stream,
                           Wq0, H, out, out + TBH);
    } else {
        hipLaunchKernelGGL(rnn_scan4, dim3(128), dim3(512), 0, stream,
                           Wq0, H, out, out + TBH, X);
    }

    // 4) pre1 = states0 @ Wx1^T + b_deep (in-place over d_out)
    hipLaunchKernelGGL(xproj_f16, dim3((TT * BB) / 32), dim3(1024),
                       32 * (HH / 2) * sizeof(unsigned), stream,
                       out, Wp1, bdeep, out, HH);

    // 5) layer-1 scan
    if (scan5_ok) {
        hipLaunchKernelGGL(rnn_scan5, dim3(64), dim3(512), SMEM_SCAN_BYTES, stream,
                           Wq1, H + (size_t)BB * HH, out, out + TBH + (size_t)BB * HH);
    } else {
        hipLaunchKernelGGL(rnn_scan4, dim3(128), dim3(512), 0, stream,
                           Wq1, H + (size_t)BB * HH, out, out + TBH + (size_t)BB * HH, X);
    }
}